// Round 8
// baseline (454.825 us; speedup 1.0000x reference)
//
#include <hip/hip_runtime.h>

typedef __attribute__((ext_vector_type(4))) int int4v;
typedef __attribute__((ext_vector_type(4))) float f4;

#define AS1 __attribute__((address_space(1)))
#define AS3 __attribute__((address_space(3)))

#define BAR()    __builtin_amdgcn_s_barrier()
#define LGKM0()  asm volatile("s_waitcnt lgkmcnt(0)" ::: "memory")
#define VMCNT0() asm volatile("s_waitcnt vmcnt(0)" ::: "memory")

// Producer staging: one wave issues 16 global_load_lds (each instr = 64
// lanes x 16B = 8 rows x 128B). Linear LDS dest, source pre-swizzled
// (rule #21; same involution as the ds_read side).
#define PISSUE(srcbase, k0, ulo, rgn) \
    { _Pragma("unroll") for (int u = (ulo); u < (ulo) + 16; ++u) \
        __builtin_amdgcn_global_load_lds( \
            (const AS1 void*)((srcbase) + (size_t)(u) * 8 * K + (k0)), \
            (AS3 void*)(ls + (rgn) + (u) * 1024 + (lane << 4)), 16, 0, 0); }

#define LDA(mq, sb) \
    { _Pragma("unroll") for (int m = 0; m < 4; ++m) { \
        const int rb = (sb) + ((aRow0 + ((mq) << 6) + (m << 4)) << 7); \
        a[m][0] = *(const int4v*)(ls + rb + colx0); \
        a[m][1] = *(const int4v*)(ls + rb + colx1); } }

#define LDB(nq, sb) \
    { _Pragma("unroll") for (int n = 0; n < 2; ++n) { \
        const int rb = (sb) + 32768 + ((bRow0 + ((nq) << 5) + (n << 4)) << 7); \
        b[(nq)*2 + n][0] = *(const int4v*)(ls + rb + colx0); \
        b[(nq)*2 + n][1] = *(const int4v*)(ls + rb + colx1); } }

#define MMA(mq, nq) \
    { __builtin_amdgcn_s_setprio(1); \
      _Pragma("unroll") for (int m = 0; m < 4; ++m) \
      _Pragma("unroll") for (int n = 0; n < 2; ++n) { \
        acc[(mq)*4 + m][(nq)*2 + n] = __builtin_amdgcn_mfma_i32_16x16x64_i8( \
            a[m][0], b[(nq)*2 + n][0], acc[(mq)*4 + m][(nq)*2 + n], 0, 0, 0); \
        acc[(mq)*4 + m][(nq)*2 + n] = __builtin_amdgcn_mfma_i32_16x16x64_i8( \
            a[m][1], b[(nq)*2 + n][1], acc[(mq)*4 + m][(nq)*2 + n], 0, 0, 0); } \
      __builtin_amdgcn_s_setprio(0); }

// ---------------------------------------------------------------------------
// Pack int32->int8: 64B vector reads -> 16B vector store per thread-iter.
__global__ __launch_bounds__(256) void pack16_kernel(
    const int* __restrict__ x, const int* __restrict__ w,
    int4v* __restrict__ x8, int4v* __restrict__ w8, int n16x, int n16w)
{
    int i = blockIdx.x * blockDim.x + threadIdx.x;
    const int stride = gridDim.x * blockDim.x;
    const int tot = n16x + n16w;
    for (; i < tot; i += stride) {
        const bool isx = i < n16x;
        const int4v* src = isx ? (const int4v*)x + (size_t)i * 4
                               : (const int4v*)w + (size_t)(i - n16x) * 4;
        int4v o;
#pragma unroll
        for (int q = 0; q < 4; ++q) {
            const int4v v = src[q];
            o[q] = (v.x & 255) | ((v.y & 255) << 8) | ((v.z & 255) << 16) | ((v.w & 255) << 24);
        }
        if (isx) x8[i] = o; else w8[i - n16x] = o;
    }
}

// ---------------------------------------------------------------------------
// Persistent 256x256 GEMM, 8 waves. Waves 0 (A) / 1 (B) issue ALL
// global_load_lds and are the ONLY waves executing vmcnt gates; waves 2-7
// never wait on vmcnt, so epilogue stores drain async under the next tile's
// K-loop. Epilogue: per-wave LDS transpose -> dwordx4 stores (FIXED: full
// 16x32 tile read-back; round 7 only stored cols 0-15 of each 32-block).
// LDS: R0 @0 (A 32K | B 32K), R1 @65536, transpose scratch @131072 (16KB).
__global__ __launch_bounds__(512, 2) void gemm_i8_prod(
    const char* __restrict__ A8, const char* __restrict__ B8,
    const float* __restrict__ scale, const int* __restrict__ bias,
    float* __restrict__ out, int M, int N, int K,
    int mTiles, int nTiles, int chunked)
{
    extern __shared__ __attribute__((aligned(16))) char ls[];

    const int tid  = threadIdx.x;
    const int lane = tid & 63;
    const int wid  = tid >> 6;
    const int wr   = wid >> 2;      // 0..1 (M half)
    const int wc   = wid & 3;       // 0..3 (N quarter)
    const int l15  = lane & 15;
    const int hi16 = lane >> 4;

    const int sw    = (l15 & 7) << 4;
    const int colx0 = ((hi16 << 4)) ^ sw;
    const int colx1 = (64 + (hi16 << 4)) ^ sw;
    const int aRow0 = (wr << 7) + l15;
    const int bRow0 = (wc << 6) + l15;

    const int prow = lane >> 3;
    const int pcol = (((lane & 7) ^ prow) << 4);

    const int nkt = K >> 7;
    const int nit = nkt >> 1;
    const int nwg = mTiles * nTiles;
    const int grid = (int)gridDim.x;

    int4v acc[8][4];
    int4v a[4][2], b[4][2];

    bool first = true;

    for (int idx = blockIdx.x; idx < nwg; idx += grid) {
        int mt, nt, mtn = 0, ntn = 0;
        if (chunked) {
            const int x = idx & 7, c = idx >> 3;
            mt = x * (mTiles >> 3) + c / nTiles;
            nt = c % nTiles;
        } else { mt = idx / nTiles; nt = idx % nTiles; }
        const int nidx = idx + grid;
        const bool hasNext = nidx < nwg;
        if (hasNext) {
            if (chunked) {
                const int x = nidx & 7, c = nidx >> 3;
                mtn = x * (mTiles >> 3) + c / nTiles;
                ntn = c % nTiles;
            } else { mtn = nidx / nTiles; ntn = nidx % nTiles; }
        }
        const int m0 = mt << 8, n0 = nt << 8;
        const char* aSrcBase  = A8 + (size_t)(m0 + prow) * K + pcol;
        const char* bSrcBase  = B8 + (size_t)(n0 + prow) * K + pcol;
        const char* aSrcBaseN = A8 + (size_t)((mtn << 8) + prow) * K + pcol;
        const char* bSrcBaseN = B8 + (size_t)((ntn << 8) + prow) * K + pcol;

#pragma unroll
        for (int i = 0; i < 8; ++i)
#pragma unroll
            for (int j = 0; j < 4; ++j)
                acc[i][j] = (int4v){0, 0, 0, 0};

        if (first) {
            if (wid == 0)      { PISSUE(aSrcBase, 0, 0, 0); PISSUE(aSrcBase, 0, 16, 0); }
            else if (wid == 1) { PISSUE(bSrcBase, 0, 0, 32768); PISSUE(bSrcBase, 0, 16, 32768); }
            if (wid < 2) VMCNT0();
            BAR();
            first = false;
        }

#pragma unroll 1
        for (int it = 0; it < nit; ++it) {
            const int kR1 = (2 * it + 1) << 7;
            const int tE  = 2 * it + 2;
            const bool hk = tE < nkt;
            const bool doN = hk || hasNext;
            const char* nA = hk ? aSrcBase : aSrcBaseN;
            const char* nB = hk ? bSrcBase : bSrcBaseN;
            const int   kN = hk ? (tE << 7) : 0;

            // g0: compute R0 (mq0,nq0) | producers issue R1 u0-15
            LDB(0, 0); LDA(0, 0);
            if (wid == 0)      PISSUE(aSrcBase, kR1, 0, 65536)
            else if (wid == 1) PISSUE(bSrcBase, kR1, 0, 65536 + 32768)
            BAR(); LGKM0();
            MMA(0, 0);
            BAR();

            // g1: (mq0,nq1) | R1 u16-31
            LDB(1, 0);
            if (wid == 0)      PISSUE(aSrcBase, kR1, 16, 65536)
            else if (wid == 1) PISSUE(bSrcBase, kR1, 16, 65536 + 32768)
            BAR(); LGKM0();
            MMA(0, 1);
            BAR();

            // g2: (mq1,nq1)
            LDA(1, 0);
            BAR(); LGKM0();
            MMA(1, 1);
            BAR();

            // g3: (mq1,nq0) | gate: R1 ready (producers only)
            BAR(); LGKM0();
            MMA(1, 0);
            if (wid < 2) VMCNT0();
            BAR();

            // g4: compute R1 (mq0,nq0) | producers issue next R0 u0-15
            LDB(0, 65536); LDA(0, 65536);
            if (wid == 0 && doN)      PISSUE(nA, kN, 0, 0)
            else if (wid == 1 && doN) PISSUE(nB, kN, 0, 32768)
            BAR(); LGKM0();
            MMA(0, 0);
            BAR();

            // g5: (mq0,nq1) | next R0 u16-31
            LDB(1, 65536);
            if (wid == 0 && doN)      PISSUE(nA, kN, 16, 0)
            else if (wid == 1 && doN) PISSUE(nB, kN, 16, 32768)
            BAR(); LGKM0();
            MMA(0, 1);
            BAR();

            // g6: (mq1,nq1)
            LDA(1, 65536);
            BAR(); LGKM0();
            MMA(1, 1);
            BAR();

            // g7: (mq1,nq0) | gate: next R0 ready
            BAR(); LGKM0();
            MMA(1, 0);
            if (wid < 2) VMCNT0();
            BAR();
        }

        // epilogue: scale/bias -> per-wave LDS transpose -> dwordx4 stores.
        // Stores by waves 2-7 are NEVER gated (async drain under next tile).
        float scl[4]; int bsv[4];
#pragma unroll
        for (int nj = 0; nj < 4; ++nj) {
            const int col = n0 + (wc << 6) + (nj << 4) + l15;
            scl[nj] = scale[col];
            bsv[nj] = bias[col];
        }
        float* scr = (float*)(ls + 131072 + (wid << 11));   // 2KB per wave
        const int rr = lane >> 3;        // 0..7 (row, and row+8)
        const int sg = lane & 7;         // 0..7 -> col group of 4 in [0,32)
#pragma unroll
        for (int mi = 0; mi < 8; ++mi) {
#pragma unroll 1
            for (int njh = 0; njh < 2; ++njh) {
#pragma unroll
                for (int njl = 0; njl < 2; ++njl) {
                    const int nj = (njh << 1) + njl;
#pragma unroll
                    for (int r = 0; r < 4; ++r) {
                        scr[((hi16 << 2) + r) * 32 + (njl << 4) + l15] =
                            (float)(acc[mi][nj][r] + bsv[nj]) * scl[nj];
                    }
                }
                LGKM0();
                // full 16x32 read-back: each lane covers rows rr and rr+8
                const f4 v0 = *(const f4*)&scr[rr * 32 + (sg << 2)];
                const f4 v1 = *(const f4*)&scr[(rr + 8) * 32 + (sg << 2)];
                const int grow = m0 + (wr << 7) + (mi << 4) + rr;
                const int gcol = n0 + (wc << 6) + (njh << 5) + (sg << 2);
                *(f4*)(out + (size_t)grow * N + gcol) = v0;
                *(f4*)(out + (size_t)(grow + 8) * N + gcol) = v1;
            }
        }
        LGKM0();   // scratch reads done before next tile's ds activity
    }
}

// ---------------------------------------------------------------------------
__global__ __launch_bounds__(256) void naive_kernel(
    const int* __restrict__ x, const int* __restrict__ w,
    const float* __restrict__ scale, const int* __restrict__ bias,
    float* __restrict__ out, int M, int N, int K)
{
    size_t idx = (size_t)blockIdx.x * blockDim.x + threadIdx.x;
    const size_t total = (size_t)M * N;
    const size_t stride = (size_t)gridDim.x * blockDim.x;
    for (; idx < total; idx += stride) {
        const int m = (int)(idx / N), n = (int)(idx % N);
        int acc = 0;
        for (int k = 0; k < K; ++k) acc += x[(size_t)m * K + k] * w[(size_t)n * K + k];
        out[idx] = (float)(acc + bias[n]) * scale[n];
    }
}

// ---------------------------------------------------------------------------
extern "C" void kernel_launch(void* const* d_in, const int* in_sizes, int n_in,
                              void* d_out, int out_size, void* d_ws, size_t ws_size,
                              hipStream_t stream)
{
    const int*   x     = (const int*)d_in[0];
    const int*   w     = (const int*)d_in[1];
    const float* scale = (const float*)d_in[2];
    const int*   bias  = (const int*)d_in[3];
    float*       out   = (float*)d_out;

    const int N = in_sizes[2];
    const int K = in_sizes[1] / N;
    const int M = in_sizes[0] / K;

    const size_t needA = (size_t)M * K;
    const size_t needB = (size_t)N * K;

    if (ws_size < needA + needB || (M % 256) || (N % 256) || (K % 256)) {
        naive_kernel<<<8192, 256, 0, stream>>>(x, w, scale, bias, out, M, N, K);
        return;
    }

    char* x8 = (char*)d_ws;
    char* w8 = x8 + needA;

    pack16_kernel<<<2048, 256, 0, stream>>>(x, w, (int4v*)x8, (int4v*)w8,
                                            (int)(needA >> 4), (int)(needB >> 4));

    hipFuncSetAttribute((const void*)gemm_i8_prod,
                        hipFuncAttributeMaxDynamicSharedMemorySize, 147456);

    const int mTiles = M / 256, nTiles = N / 256;
    const int nwg = mTiles * nTiles;
    const int grid = nwg < 256 ? nwg : 256;
    const int chunked = (mTiles % 8 == 0) ? 1 : 0;
    gemm_i8_prod<<<grid, 512, 147456, stream>>>(x8, w8, scale, bias, out,
                                                M, N, K, mTiles, nTiles, chunked);
}

// Round 10
// 243.900 us; speedup vs baseline: 1.8648x; 1.8648x over previous
//
#include <hip/hip_runtime.h>

typedef __attribute__((ext_vector_type(4))) int int4v;
typedef __attribute__((ext_vector_type(4))) float f4;

#define AS1 __attribute__((address_space(1)))
#define AS3 __attribute__((address_space(3)))

#define BAR()    __builtin_amdgcn_s_barrier()
#define LGKM0()  asm volatile("s_waitcnt lgkmcnt(0)" ::: "memory")
#define VM0()    asm volatile("s_waitcnt vmcnt(0)" ::: "memory")
#define VM6()    asm volatile("s_waitcnt vmcnt(6)" ::: "memory")
#define VM38()   asm volatile("s_waitcnt vmcnt(38)" ::: "memory")

// stage one 64-row x 128B unit (all 512 threads; 1 vmem instr per wave).
// LDS dest linear, global source inverse-swizzled (rule #21).
#define STG2(srcb, ldsbase, sb, rowbase, k0) \
    __builtin_amdgcn_global_load_lds( \
        (const AS1 void*)((srcb) + (size_t)(rowbase) * K + (k0)), \
        (AS3 void*)((ldsbase) + (sb) + (rowbase) * 128), 16, 0, 0)

#define LDA(mq, sb) \
    { _Pragma("unroll") for (int m = 0; m < 4; ++m) { \
        const int rb = (sb) + ((aRow0 + ((mq) << 6) + (m << 4)) << 7); \
        a[m][0] = *(const int4v*)(ls + rb + colx0); \
        a[m][1] = *(const int4v*)(ls + rb + colx1); } }

#define LDB(nq, sb) \
    { _Pragma("unroll") for (int n = 0; n < 2; ++n) { \
        const int rb = (sb) + 32768 + ((bRow0 + ((nq) << 5) + (n << 4)) << 7); \
        b[(nq)*2 + n][0] = *(const int4v*)(ls + rb + colx0); \
        b[(nq)*2 + n][1] = *(const int4v*)(ls + rb + colx1); } }

#define MMA(mq, nq) \
    { __builtin_amdgcn_s_setprio(1); \
      _Pragma("unroll") for (int m = 0; m < 4; ++m) \
      _Pragma("unroll") for (int n = 0; n < 2; ++n) { \
        acc[(mq)*4 + m][(nq)*2 + n] = __builtin_amdgcn_mfma_i32_16x16x64_i8( \
            a[m][0], b[(nq)*2 + n][0], acc[(mq)*4 + m][(nq)*2 + n], 0, 0, 0); \
        acc[(mq)*4 + m][(nq)*2 + n] = __builtin_amdgcn_mfma_i32_16x16x64_i8( \
            a[m][1], b[(nq)*2 + n][1], acc[(mq)*4 + m][(nq)*2 + n], 0, 0, 0); } \
      __builtin_amdgcn_s_setprio(0); }

// ---------------------------------------------------------------------------
__global__ __launch_bounds__(256) void pack16_kernel(
    const int* __restrict__ x, const int* __restrict__ w,
    int4v* __restrict__ x8, int4v* __restrict__ w8, int n16x, int n16w)
{
    int i = blockIdx.x * blockDim.x + threadIdx.x;
    const int stride = gridDim.x * blockDim.x;
    const int tot = n16x + n16w;
    for (; i < tot; i += stride) {
        const bool isx = i < n16x;
        const int4v* src = isx ? (const int4v*)x + (size_t)i * 4
                               : (const int4v*)w + (size_t)(i - n16x) * 4;
        int4v o;
#pragma unroll
        for (int q = 0; q < 4; ++q) {
            const int4v v = src[q];
            o[q] = (v.x & 255) | ((v.y & 255) << 8) | ((v.z & 255) << 16) | ((v.w & 255) << 24);
        }
        if (isx) x8[i] = o; else w8[i - n16x] = o;
    }
}

// ---------------------------------------------------------------------------
// Persistent 256x256 GEMM with seamless tile transitions. The last K-iter
// pre-stages the NEXT tile's k0+k1 (incl. tails) before the epilogue stores,
// so the next tile's first gate is vmcnt(38): by in-order vmem retirement it
// waits exactly for k1's loads while all 32 epilogue stores stay in flight.
// FIX vs round 9: the final tile (fill==false) g3 gate must DRAIN (vmcnt(0));
// VM6 left 2 of 8 slot1 writes unlanded -> race -> absmax 3688.
// LDS: slot0 @0, slot1 @65536 (A|B 32K each); epilogue scratch @131072.
__global__ __launch_bounds__(512, 2) void gemm_i8_seam(
    const char* __restrict__ A8, const char* __restrict__ B8,
    const float* __restrict__ scale, const int* __restrict__ bias,
    float* __restrict__ out, int M, int N, int K,
    int mTiles, int nTiles, int chunked)
{
    extern __shared__ __attribute__((aligned(16))) char ls[];

    const int tid  = threadIdx.x;
    const int lane = tid & 63;
    const int wid  = tid >> 6;
    const int wr   = wid >> 2;
    const int wc   = wid & 3;
    const int l15  = lane & 15;
    const int hi16 = lane >> 4;

    const int sw    = (l15 & 7) << 4;
    const int colx0 = ((hi16 << 4)) ^ sw;
    const int colx1 = (64 + (hi16 << 4)) ^ sw;
    const int aRow0 = (wr << 7) + l15;
    const int bRow0 = (wc << 6) + l15;

    const int srow  = tid >> 3;
    const int sslot = tid & 7;
    const int scol  = ((sslot ^ (srow & 7)) << 4);
    char* ldsDestA = ls + srow * 128 + (sslot << 4);
    char* ldsDestB = ls + 32768 + srow * 128 + (sslot << 4);

    const int nkt = K >> 7;
    const int nit = nkt >> 1;           // >= 2 (host guarantees K % 256 == 0)
    const int nwg = mTiles * nTiles;
    const int grid = (int)gridDim.x;

    int4v acc[8][4];
    int4v a[4][2], b[4][2];

    for (int idx = blockIdx.x; idx < nwg; idx += grid) {
        const bool firstTile = (idx == (int)blockIdx.x);
        int mt, nt, mtn = 0, ntn = 0;
        if (chunked) {
            const int x = idx & 7, c = idx >> 3;
            mt = x * (mTiles >> 3) + c / nTiles;
            nt = c % nTiles;
        } else { mt = idx / nTiles; nt = idx % nTiles; }
        const int nidx = idx + grid;
        const bool hasNext = nidx < nwg;
        if (hasNext) {
            if (chunked) {
                const int x = nidx & 7, c = nidx >> 3;
                mtn = x * (mTiles >> 3) + c / nTiles;
                ntn = c % nTiles;
            } else { mtn = nidx / nTiles; ntn = nidx % nTiles; }
        }
        const int m0 = mt << 8, n0 = nt << 8;
        const char* aSrc  = A8 + (size_t)(m0 + srow) * K + scol;
        const char* bSrc  = B8 + (size_t)(n0 + srow) * K + scol;
        const char* aSrcN = A8 + (size_t)((mtn << 8) + srow) * K + scol;
        const char* bSrcN = B8 + (size_t)((ntn << 8) + srow) * K + scol;

#pragma unroll
        for (int i = 0; i < 8; ++i)
#pragma unroll
            for (int j = 0; j < 4; ++j)
                acc[i][j] = (int4v){0, 0, 0, 0};

        if (firstTile) {
            // cold prologue: k0 (8 units) -> slot0; k1 first 6 -> slot1
            STG2(aSrc, ldsDestA, 0, 0, 0);   STG2(aSrc, ldsDestA, 0, 128, 0);
            STG2(aSrc, ldsDestA, 0, 64, 0);  STG2(aSrc, ldsDestA, 0, 192, 0);
            STG2(bSrc, ldsDestB, 0, 0, 0);   STG2(bSrc, ldsDestB, 0, 64, 0);
            STG2(bSrc, ldsDestB, 0, 128, 0); STG2(bSrc, ldsDestB, 0, 192, 0);
            STG2(aSrc, ldsDestA, 65536, 0, 128); STG2(aSrc, ldsDestA, 65536, 128, 128);
            STG2(bSrc, ldsDestB, 65536, 0, 128); STG2(bSrc, ldsDestB, 65536, 64, 128);
            STG2(bSrc, ldsDestB, 65536, 128, 128); STG2(bSrc, ldsDestB, 65536, 192, 128);
            VM6();
            BAR();
        }
        // else: k0/k1 pre-staged by the previous tile's last iteration.

#pragma unroll 1
        for (int it = 0; it < nit; ++it) {
            const bool bnd    = (!firstTile) && (it == 0);
            const bool lastIt = (it == nit - 1);
            const bool fill   = (!lastIt) || hasNext;
            const char* fA = lastIt ? aSrcN : aSrc;
            const char* fB = lastIt ? bSrcN : bSrc;
            const int  kE2 = lastIt ? 0   : ((2 * it + 2) << 7);
            const int  kO2 = lastIt ? 128 : ((2 * it + 3) << 7);
            const int  kT  = (2 * it + 1) << 7;    // current slot1 tails

            // g0: compute slot0 (mq0,nq0) | tails of current k-odd -> slot1
            LDA(0, 0); LDB(0, 0);
            if (!bnd) { STG2(aSrc, ldsDestA, 65536, 64, kT); STG2(aSrc, ldsDestA, 65536, 192, kT); }
            BAR(); LGKM0();
            MMA(0, 0);
            BAR();

            // g1: (mq0,nq1) | fill slot0 uA0,uA1
            LDB(1, 0);
            if (fill) { STG2(fA, ldsDestA, 0, 0, kE2); STG2(fA, ldsDestA, 0, 128, kE2); }
            BAR(); LGKM0();
            MMA(0, 1);
            BAR();

            // g2: (mq1,nq1) | fill slot0 uB0,uB1
            LDA(1, 0);
            if (fill) { STG2(fB, ldsDestB, 0, 0, kE2); STG2(fB, ldsDestB, 0, 64, kE2); }
            BAR(); LGKM0();
            MMA(1, 1);
            BAR();

            // g3: (mq1,nq0) | fill slot0 uB2,uB3 | gate slot1
            if (fill) { STG2(fB, ldsDestB, 0, 128, kE2); STG2(fB, ldsDestB, 0, 192, kE2); }
            BAR(); LGKM0();
            MMA(1, 0);
            if (bnd)      { VM38(); }
            else if (fill){ VM6();  }
            else          { VM0();  }   // final tile: drain ALL 8 slot1 writes
            BAR();

            // g4: compute slot1 (mq0,nq0) | fill slot0 uA2,uA3
            LDA(0, 65536); LDB(0, 65536);
            if (fill) { STG2(fA, ldsDestA, 0, 64, kE2); STG2(fA, ldsDestA, 0, 192, kE2); }
            BAR(); LGKM0();
            MMA(0, 0);
            BAR();

            // g5: (mq0,nq1) | fill slot1 uA0,uA1
            LDB(1, 65536);
            if (fill) { STG2(fA, ldsDestA, 65536, 0, kO2); STG2(fA, ldsDestA, 65536, 128, kO2); }
            BAR(); LGKM0();
            MMA(0, 1);
            BAR();

            // g6: (mq1,nq1) | fill slot1 uB0,uB1
            LDA(1, 65536);
            if (fill) { STG2(fB, ldsDestB, 65536, 0, kO2); STG2(fB, ldsDestB, 65536, 64, kO2); }
            BAR(); LGKM0();
            MMA(1, 1);
            BAR();

            // g7: (mq1,nq0) | fill slot1 uB2,uB3 (+ tails if seam) | gate slot0
            if (fill) {
                STG2(fB, ldsDestB, 65536, 128, kO2); STG2(fB, ldsDestB, 65536, 192, kO2);
                if (lastIt) { STG2(fA, ldsDestA, 65536, 64, kO2); STG2(fA, ldsDestA, 65536, 192, kO2); }
            }
            BAR(); LGKM0();
            MMA(1, 0);
            if (fill) { VM6(); }
            BAR();
        }

        // epilogue: scale/bias -> per-wave LDS transpose (stride 36, pad) ->
        // 32 dwordx4 stores/wave. Stores stay in flight under the next tile's
        // K-loop (first gate = vmcnt(38) tolerates all 32).
        float scl[4]; int bsv[4];
#pragma unroll
        for (int nj = 0; nj < 4; ++nj) {
            const int col = n0 + (wc << 6) + (nj << 4) + l15;
            scl[nj] = scale[col];
            bsv[nj] = bias[col];
        }
        float* scr = (float*)(ls + 131072) + wid * 576;   // 16 x 36 floats
        const int rr = lane >> 3;
        const int sg = lane & 7;
#pragma unroll
        for (int mi = 0; mi < 8; ++mi) {
#pragma unroll 1
            for (int njh = 0; njh < 2; ++njh) {
#pragma unroll
                for (int njl = 0; njl < 2; ++njl) {
                    const int nj = (njh << 1) + njl;
#pragma unroll
                    for (int r = 0; r < 4; ++r) {
                        scr[((hi16 << 2) + r) * 36 + (njl << 4) + l15] =
                            (float)(acc[mi][nj][r] + bsv[nj]) * scl[nj];
                    }
                }
                LGKM0();
                const f4 v0 = *(const f4*)&scr[rr * 36 + (sg << 2)];
                const f4 v1 = *(const f4*)&scr[(rr + 8) * 36 + (sg << 2)];
                const int grow = m0 + (wr << 7) + (mi << 4) + rr;
                const int gcol = n0 + (wc << 6) + (njh << 5) + (sg << 2);
                *(f4*)(out + (size_t)grow * N + gcol) = v0;
                *(f4*)(out + (size_t)(grow + 8) * N + gcol) = v1;
            }
        }
        LGKM0();
        asm volatile("" ::: "memory");   // pin stores before next tile's staging
    }
}

// ---------------------------------------------------------------------------
__global__ __launch_bounds__(256) void naive_kernel(
    const int* __restrict__ x, const int* __restrict__ w,
    const float* __restrict__ scale, const int* __restrict__ bias,
    float* __restrict__ out, int M, int N, int K)
{
    size_t idx = (size_t)blockIdx.x * blockDim.x + threadIdx.x;
    const size_t total = (size_t)M * N;
    const size_t stride = (size_t)gridDim.x * blockDim.x;
    for (; idx < total; idx += stride) {
        const int m = (int)(idx / N), n = (int)(idx % N);
        int acc = 0;
        for (int k = 0; k < K; ++k) acc += x[(size_t)m * K + k] * w[(size_t)n * K + k];
        out[idx] = (float)(acc + bias[n]) * scale[n];
    }
}

// ---------------------------------------------------------------------------
extern "C" void kernel_launch(void* const* d_in, const int* in_sizes, int n_in,
                              void* d_out, int out_size, void* d_ws, size_t ws_size,
                              hipStream_t stream)
{
    const int*   x     = (const int*)d_in[0];
    const int*   w     = (const int*)d_in[1];
    const float* scale = (const float*)d_in[2];
    const int*   bias  = (const int*)d_in[3];
    float*       out   = (float*)d_out;

    const int N = in_sizes[2];
    const int K = in_sizes[1] / N;
    const int M = in_sizes[0] / K;

    const size_t needA = (size_t)M * K;
    const size_t needB = (size_t)N * K;

    if (ws_size < needA + needB || (M % 256) || (N % 256) || (K % 256)) {
        naive_kernel<<<8192, 256, 0, stream>>>(x, w, scale, bias, out, M, N, K);
        return;
    }

    char* x8 = (char*)d_ws;
    char* w8 = x8 + needA;

    pack16_kernel<<<2048, 256, 0, stream>>>(x, w, (int4v*)x8, (int4v*)w8,
                                            (int)(needA >> 4), (int)(needB >> 4));

    hipFuncSetAttribute((const void*)gemm_i8_seam,
                        hipFuncAttributeMaxDynamicSharedMemorySize, 149504);

    const int mTiles = M / 256, nTiles = N / 256;
    const int nwg = mTiles * nTiles;
    const int grid = nwg < 256 ? nwg : 256;
    const int chunked = (mTiles % 8 == 0) ? 1 : 0;
    gemm_i8_seam<<<grid, 512, 149504, stream>>>(x8, w8, scale, bias, out,
                                                M, N, K, mTiles, nTiles, chunked);
}